// Round 9
// baseline (483.054 us; speedup 1.0000x reference)
//
#include <hip/hip_runtime.h>
#include <math.h>
#include <stdint.h>

// Problem constants
#define S_LEN 2048
#define HID 4096
#define NH 32
#define NKV 8
#define HD 128
#define QKV_N ((NH + 2*NKV) * HD)   // 6144
#define NQK (NH + NKV)              // 40
static __device__ __constant__ const float SCALE_F = 0.08838834764831845f; // 128^-0.5

typedef __bf16 bf16x8 __attribute__((ext_vector_type(8)));
typedef __bf16 bf16x4 __attribute__((ext_vector_type(4)));
typedef float  f32x4  __attribute__((ext_vector_type(4)));
typedef uint32_t u32x4 __attribute__((ext_vector_type(4)));

#define GLD_LDS(gptr, lptr) \
  __builtin_amdgcn_global_load_lds( \
      (const __attribute__((address_space(1))) uint32_t*)(gptr), \
      (__attribute__((address_space(3))) uint32_t*)(lptr), 16, 0, 0)

// ---------- 64x64 transpose+cast tile helper: out[c][r] = (bf16)in[r][c] ----------
__device__ __forceinline__ void tp64(const float* __restrict__ in, __bf16* __restrict__ out,
                                     int R, int C, int bx, int by, int tid, float* tile) {
  int lr = tid >> 4;           // 0..15
  int lc = (tid & 15) * 4;     // 0..60
  #pragma unroll
  for (int p = 0; p < 4; ++p) {
    int r = p * 16 + lr;
    const float4 v = *(const float4*)&in[(size_t)(by + r) * C + bx + lc];
    float* t = &tile[r * 65 + lc];
    t[0] = v.x; t[1] = v.y; t[2] = v.z; t[3] = v.w;
  }
  __syncthreads();
  int oc = tid >> 5;           // 0..7
  int orr = (tid & 31) * 2;
  #pragma unroll
  for (int p = 0; p < 8; ++p) {
    int c = p * 8 + oc;
    float v0 = tile[orr * 65 + c];
    float v1 = tile[(orr + 1) * 65 + c];
    __bf16 b2[2] = { (__bf16)v0, (__bf16)v1 };
    *(uint32_t*)&out[(size_t)(bx + c) * R + by + orr] = *(uint32_t*)b2;
  }
}

// ---------- fused prep: cast hidden -> bf16 | transpose Wqkv | transpose Wo ----------
__global__ __launch_bounds__(256) void fused_prep_kernel(const float* __restrict__ hidden,
                                                         __bf16* __restrict__ hid_bf,
                                                         const float* __restrict__ Wqkv,
                                                         __bf16* __restrict__ wqkvT,
                                                         const float* __restrict__ Wo,
                                                         __bf16* __restrict__ woT) {
  __shared__ float tile[64 * 65];
  const int b = blockIdx.x;
  const int tid = threadIdx.x;
  if (b < 2048) {
    const float4* in4 = (const float4*)hidden;
    int i = b * 256 + tid;
    #pragma unroll
    for (int k = 0; k < 4; ++k) {
      float4 v = in4[i + k * 524288];
      bf16x4 o = { (__bf16)v.x, (__bf16)v.y, (__bf16)v.z, (__bf16)v.w };
      *(bf16x4*)(hid_bf + (size_t)(i + k * 524288) * 4) = o;
    }
  } else if (b < 8192) {
    int id = b - 2048;                 // 96 x 64 tiles
    int bx = (id % 96) * 64, by = (id / 96) * 64;
    tp64(Wqkv, wqkvT, HID, QKV_N, bx, by, tid, tile);
  } else {
    int id = b - 8192;                 // 64 x 64 tiles
    int bx = (id & 63) * 64, by = (id >> 6) * 64;
    tp64(Wo, woT, HID, HID, bx, by, tid, tile);
  }
}

// ---------- fused rope + V-transpose ----------
__global__ __launch_bounds__(256) void fused_rope_tpv_kernel(const __bf16* __restrict__ qkv,
                                                             const int* __restrict__ pos,
                                                             __bf16* __restrict__ Qr,
                                                             __bf16* __restrict__ Kr,
                                                             __bf16* __restrict__ Vt) {
  __shared__ __bf16 tile[32][33];
  const int b = blockIdx.x;
  const int tid = threadIdx.x;
  if (b < 20480) {
    int idx = b * 256 + tid;
    int half = idx & 63;
    int t = idx >> 6;
    int hh = t % NQK;
    int s = t / NQK;
    if (s >= S_LEN) return;
    float p = (float)pos[s];
    float inv_freq = exp2f((float)half * -0.2076205059304601f);
    float ang = p * inv_freq;
    float cs = cosf(ang), sn = sinf(ang);
    const __bf16* src; __bf16* dst;
    if (hh < NH) {
      src = qkv + (size_t)s * QKV_N + (size_t)hh * HD;
      dst = Qr + ((size_t)s * NH + hh) * HD;
    } else {
      int kh = hh - NH;
      src = qkv + (size_t)s * QKV_N + (size_t)NH * HD + (size_t)kh * HD;
      dst = Kr + ((size_t)s * NKV + kh) * HD;
    }
    float x1 = (float)src[half], x2 = (float)src[half + 64];
    dst[half]      = (__bf16)(x1 * cs - x2 * sn);
    dst[half + 64] = (__bf16)(x2 * cs + x1 * sn);
  } else {
    int id = b - 20480;
    int sb = (id & 63) * 32;
    int db = ((id >> 6) & 3) * 32;
    int kvh = id >> 8;
    int tx = tid & 31, ty = tid >> 5;
    const __bf16* src = qkv + (size_t)(NH + NKV) * HD + (size_t)kvh * HD;
    for (int i = 0; i < 32; i += 8)
      tile[ty + i][tx] = src[(size_t)(sb + ty + i) * QKV_N + db + tx];
    __syncthreads();
    for (int i = 0; i < 32; i += 8)
      Vt[((size_t)kvh * HD + db + ty + i) * S_LEN + sb + tx] = tile[tx][ty + i];
  }
}

// ===================================================================================
// 256x256-tile 8-phase bf16 GEMM — R9: m201-exact phase timing.
// Phase p = { issue 4-or-8 ds_read_b128 (THIS phase's operands) ; issue 1 half-tile
// stage ; [vmcnt(4) at p3/p7] ; s_barrier ; lgkmcnt(0) ; setprio 16xMFMA ; s_barrier }.
// Read latency hides under the barrier join + other waves' MFMA (m201: 824 cyc/phase
// refcheck'd vs R4's 947). Stage order & running pointers identical to R4; LDS
// layout/swizzle unchanged (measured 0 conflicts).
// vmcnt(4) ledger: at p3 in-flight = {p6',p7',p0,p1,p2,p3} = 12 loads; wait 4 drains
// p6',p7',p0,p1 = ALL of tile t0+1 before p4 reads it; p7 symmetrical for t0+2.
// Stage-overwrite: every stage target's readers drained (lgkm0) + joined (end BAR)
// one phase earlier.
// ===================================================================================
template <typename OutT>
__global__ __launch_bounds__(512, 2) void gemm8p_kernel(const __bf16* __restrict__ A,
                                                        const __bf16* __restrict__ Bt,
                                                        OutT* __restrict__ C0,
                                                        OutT* __restrict__ C1,
                                                        int M, int N, int Kext, int ld) {
  __shared__ __align__(16) __bf16 sA[2][2][256 * 32];
  __shared__ __align__(16) __bf16 sB[2][2][256 * 32];
  const int tid = threadIdx.x;
  const int lane = tid & 63;
  const int wave = tid >> 6;
  const int quad = lane >> 4;
  const int l16 = lane & 15;
  const int wm = (wave >> 2) * 128;
  const int wn = (wave & 3) * 64;

  const int z = blockIdx.z;
  A += (size_t)z * Kext;
  Bt += (size_t)z * Kext;
  OutT* __restrict__ C = z ? C1 : C0;

  const int nx = gridDim.x;
  size_t bm, bn;
  if (gridDim.y == 8 && (nx & 7) == 0) {
    int lin = blockIdx.y * nx + blockIdx.x;
    int j = lin >> 3, xcd = lin & 7;
    bm = (size_t)(j & 7) * 256;
    bn = (size_t)(xcd * (nx >> 3) + (j >> 3)) * 256;
  } else {
    bm = (size_t)blockIdx.y * 256;
    bn = (size_t)blockIdx.x * 256;
  }

  const int NT = Kext >> 6;
  const int rsw = (l16 >> 1) & 3;

  f32x4 acc[8][4] = {};
  bf16x8 aR[4], bR[4];                // single register set (m201-style in-phase reads)

  const int row0 = tid >> 2;
  const int chL = (tid & 3) ^ ((tid >> 3) & 3);
  const uint64_t off128 = (uint64_t)128 * ld * 2;
  uint64_t aGA = (uint64_t)(uintptr_t)A + ((bm + row0) * (size_t)ld) * 2 + (size_t)chL * 16;
  uint64_t bGA = (uint64_t)(uintptr_t)Bt + ((bn + row0) * (size_t)ld) * 2 + (size_t)chL * 16;

  typedef __attribute__((address_space(3))) __bf16 lds_bf16;
  const uint32_t sAb = (uint32_t)(uintptr_t)(lds_bf16*)&sA[0][0][0];
  const uint32_t sBb = (uint32_t)(uintptr_t)(lds_bf16*)&sB[0][0][0];
  const uint32_t wlds = (uint32_t)__builtin_amdgcn_readfirstlane(wave * 1024);
  const uint32_t aBase = sAb + (uint32_t)(((wm + l16) * 32 + (quad ^ rsw) * 8) * 2);
  const uint32_t bBase = sBb + (uint32_t)(((wn + l16) * 32 + (quad ^ rsw) * 8) * 2);

#define LDSA(bf, kk) (sAb + (bf) * 32768u + (kk) * 16384u)
#define LDSB(bf, kk) (sBb + (bf) * 32768u + (kk) * 16384u)

#define STAGE_ASM(ga, ldsbase) \
  asm volatile("s_mov_b32 m0, %0\n\t" \
               "global_load_lds_dwordx4 %2, off\n\t" \
               "s_mov_b32 m0, %1\n\t" \
               "global_load_lds_dwordx4 %3, off" \
               :: "s"((ldsbase) + wlds), "s"((ldsbase) + wlds + 8192u), \
                  "v"(ga), "v"((ga) + off128) : "memory")

#define DSRD4(dst, baseaddr) do {                                                 \
    u32x4 t0_, t1_, t2_, t3_;                                                     \
    asm volatile("ds_read_b128 %0, %4\n\t"                                        \
                 "ds_read_b128 %1, %4 offset:1024\n\t"                            \
                 "ds_read_b128 %2, %4 offset:2048\n\t"                            \
                 "ds_read_b128 %3, %4 offset:3072"                                \
                 : "=&v"(t0_), "=&v"(t1_), "=&v"(t2_), "=&v"(t3_)                 \
                 : "v"(baseaddr));                                                \
    dst[0] = __builtin_bit_cast(bf16x8, t0_);                                     \
    dst[1] = __builtin_bit_cast(bf16x8, t1_);                                     \
    dst[2] = __builtin_bit_cast(bf16x8, t2_);                                     \
    dst[3] = __builtin_bit_cast(bf16x8, t3_);                                     \
  } while (0)

#define ISSUE_A(bf, kk, ih) DSRD4(aR, aBase + (bf) * 32768u + (kk) * 16384u + (ih) * 4096u)
#define ISSUE_B(bf, kk)     DSRD4(bR, bBase + (bf) * 32768u + (kk) * 16384u)

#define MFMA16(ih) do {                                                           \
    __builtin_amdgcn_s_setprio(1);                                                \
    _Pragma("unroll")                                                             \
    for (int i_ = 0; i_ < 4; ++i_)                                                \
      _Pragma("unroll")                                                           \
      for (int j_ = 0; j_ < 4; ++j_)                                              \
        acc[(ih) * 4 + i_][j_] = __builtin_amdgcn_mfma_f32_16x16x32_bf16(         \
            aR[i_], bR[j_], acc[(ih) * 4 + i_][j_], 0, 0, 0);                     \
    __builtin_amdgcn_s_setprio(0);                                                \
    __builtin_amdgcn_sched_barrier(0);                                            \
  } while (0)

#define BAR() __builtin_amdgcn_s_barrier()
#define LGKM0() do { asm volatile("s_waitcnt lgkmcnt(0)");                        \
                     __builtin_amdgcn_sched_barrier(0); } while (0)
#define VMCNT4() do { asm volatile("s_waitcnt vmcnt(4)");                         \
                      __builtin_amdgcn_sched_barrier(0); } while (0)

  // prologue: tile0 (4 halves) + tile1 k0 (6 stages = 12 loads); drain to 4; publish.
  STAGE_ASM(aGA,        LDSA(0, 0));
  STAGE_ASM(bGA,        LDSB(0, 0));
  STAGE_ASM(aGA + 64,   LDSA(0, 1));
  STAGE_ASM(bGA + 64,   LDSB(0, 1));
  STAGE_ASM(aGA + 128,  LDSA(1, 0));
  STAGE_ASM(bGA + 128,  LDSB(1, 0));
  aGA += 192; bGA += 192;
  VMCNT4();
  BAR();

  for (int u = 0; u < (NT >> 1); ++u) {
    // p0: tile t0 kk0 ih0
    ISSUE_B(0, 0); ISSUE_A(0, 0, 0);
    STAGE_ASM(aGA, LDSA(1, 1)); aGA += 64;
    BAR(); LGKM0(); MFMA16(0); BAR();
    // p1: kk0 ih1
    ISSUE_A(0, 0, 1);
    STAGE_ASM(bGA, LDSB(1, 1)); bGA += 64;
    BAR(); LGKM0(); MFMA16(1); BAR();
    // p2: kk1 ih0
    ISSUE_B(0, 1); ISSUE_A(0, 1, 0);
    STAGE_ASM(aGA, LDSA(0, 0)); aGA += 64;
    BAR(); LGKM0(); MFMA16(0); BAR();
    // p3: kk1 ih1 ; drain tile t0+1
    ISSUE_A(0, 1, 1);
    STAGE_ASM(bGA, LDSB(0, 0)); bGA += 64;
    VMCNT4();
    BAR(); LGKM0(); MFMA16(1); BAR();
    // p4: tile t0+1 kk0 ih0
    ISSUE_B(1, 0); ISSUE_A(1, 0, 0);
    STAGE_ASM(aGA, LDSA(0, 1)); aGA += 64;
    BAR(); LGKM0(); MFMA16(0); BAR();
    // p5
    ISSUE_A(1, 0, 1);
    STAGE_ASM(bGA, LDSB(0, 1)); bGA += 64;
    BAR(); LGKM0(); MFMA16(1); BAR();
    // p6
    ISSUE_B(1, 1); ISSUE_A(1, 1, 0);
    STAGE_ASM(aGA, LDSA(1, 0)); aGA += 64;
    BAR(); LGKM0(); MFMA16(0); BAR();
    // p7 ; drain tile t0+2
    ISSUE_A(1, 1, 1);
    STAGE_ASM(bGA, LDSB(1, 0)); bGA += 64;
    VMCNT4();
    BAR(); LGKM0(); MFMA16(1); BAR();
  }
  // tail stages overrun K by <=2 K-tiles (reads into adjacent live workspace only).

  asm volatile("s_waitcnt vmcnt(0) lgkmcnt(0)");
  __builtin_amdgcn_sched_barrier(0);

  #pragma unroll
  for (int i = 0; i < 8; ++i)
    #pragma unroll
    for (int j = 0; j < 4; ++j)
      #pragma unroll
      for (int r = 0; r < 4; ++r) {
        size_t row = bm + wm + i * 16 + quad * 4 + r;
        size_t col = bn + wn + j * 16 + l16;
        C[row * (size_t)N + col] = (OutT)acc[i][j][r];
      }

#undef LDSA
#undef LDSB
#undef STAGE_ASM
#undef DSRD4
#undef ISSUE_A
#undef ISSUE_B
#undef MFMA16
#undef BAR
#undef LGKM0
#undef VMCNT4
}

// ===================================================================================
// R9: BM=128 x BN=256 O-proj GEMM with m201-style phase timing.
// Per K-tile: 2 phases { 8 ds_read (this phase) ; stage kh of t+2 (3 loads) ;
// [vmcnt(6) at phase 2] ; BAR ; lgkm0 ; 16 MFMA ; BAR }. 3-deep LDS (144 KB).
// vmcnt(6) at q1: in-flight = t+1's 6 + q0's 3 + q1's 3 = 12 -> wait 6 drains
// tile t+1 before next iteration reads it. Stage target buf[(t+2)%3] last read
// at tile t-1, barrier-ordered. Tail overrun <= 2 K-tiles into live workspace.
// ===================================================================================
template <typename OutT>
__global__ __launch_bounds__(512, 2) void gemm128_kernel(const __bf16* __restrict__ A,
                                                         const __bf16* __restrict__ Bt,
                                                         OutT* __restrict__ C,
                                                         int M, int N, int K) {
  __shared__ __align__(16) __bf16 sA[3][2][128 * 32];   // 48 KB
  __shared__ __align__(16) __bf16 sB[3][2][256 * 32];   // 96 KB
  const int tid = threadIdx.x;
  const int lane = tid & 63;
  const int wave = tid >> 6;
  const int quad = lane >> 4;
  const int l16 = lane & 15;
  const int wm = (wave >> 2) * 64;
  const int wn = (wave & 3) * 64;

  const int nx = gridDim.x, ny = gridDim.y;
  const int nwg = nx * ny;
  int lin = blockIdx.y * nx + blockIdx.x;
  size_t bm, bn;
  if ((nwg & 7) == 0) {
    int swz = (lin & 7) * (nwg >> 3) + (lin >> 3);
    bm = (size_t)(swz % ny) * 128;
    bn = (size_t)(swz / ny) * 256;
  } else {
    bm = (size_t)blockIdx.y * 128;
    bn = (size_t)blockIdx.x * 256;
  }

  const int NT = K >> 6;
  const int rsw = (l16 >> 1) & 3;

  f32x4 acc[4][4] = {};
  bf16x8 aR[4], bR[4];

  const int rowA = tid >> 2;
  const int chLs = (tid & 3) ^ ((tid >> 3) & 3);
  const uint64_t off128B = (uint64_t)128 * K * 2;
  uint64_t aGA = (uint64_t)(uintptr_t)A + ((bm + rowA) * (size_t)K) * 2 + (size_t)chLs * 16;
  uint64_t bGA = (uint64_t)(uintptr_t)Bt + ((bn + rowA) * (size_t)K) * 2 + (size_t)chLs * 16;

  typedef __attribute__((address_space(3))) __bf16 lds_bf16;
  const uint32_t sAb = (uint32_t)(uintptr_t)(lds_bf16*)&sA[0][0][0];
  const uint32_t sBb = (uint32_t)(uintptr_t)(lds_bf16*)&sB[0][0][0];
  const uint32_t wlds = (uint32_t)__builtin_amdgcn_readfirstlane(wave * 1024);
  const uint32_t aBase = sAb + (uint32_t)(((wm + l16) * 32 + (quad ^ rsw) * 8) * 2);
  const uint32_t bBase = sBb + (uint32_t)(((wn + l16) * 32 + (quad ^ rsw) * 8) * 2);

#define STA128(ga, ldsoff) \
  asm volatile("s_mov_b32 m0, %0\n\t" \
               "global_load_lds_dwordx4 %1, off" \
               :: "s"((ldsoff) + wlds), "v"(ga) : "memory")

#define STB128(ga, ldsoff) \
  asm volatile("s_mov_b32 m0, %0\n\t" \
               "global_load_lds_dwordx4 %2, off\n\t" \
               "s_mov_b32 m0, %1\n\t" \
               "global_load_lds_dwordx4 %3, off" \
               :: "s"((ldsoff) + wlds), "s"((ldsoff) + wlds + 8192u), \
                  "v"(ga), "v"((ga) + off128B) : "memory")

#define DSRD4(dst, baseaddr) do {                                                 \
    u32x4 t0_, t1_, t2_, t3_;                                                     \
    asm volatile("ds_read_b128 %0, %4\n\t"                                        \
                 "ds_read_b128 %1, %4 offset:1024\n\t"                            \
                 "ds_read_b128 %2, %4 offset:2048\n\t"                            \
                 "ds_read_b128 %3, %4 offset:3072"                                \
                 : "=&v"(t0_), "=&v"(t1_), "=&v"(t2_), "=&v"(t3_)                 \
                 : "v"(baseaddr));                                                \
    dst[0] = __builtin_bit_cast(bf16x8, t0_);                                     \
    dst[1] = __builtin_bit_cast(bf16x8, t1_);                                     \
    dst[2] = __builtin_bit_cast(bf16x8, t2_);                                     \
    dst[3] = __builtin_bit_cast(bf16x8, t3_);                                     \
  } while (0)

#define IS_A(aoff, kh) DSRD4(aR, aBase + (aoff) + (kh) * 8192u)
#define IS_B(boff, kh) DSRD4(bR, bBase + (boff) + (kh) * 16384u)

#define MFMA16Q() do {                                                            \
    __builtin_amdgcn_s_setprio(1);                                                \
    _Pragma("unroll")                                                             \
    for (int i_ = 0; i_ < 4; ++i_)                                                \
      _Pragma("unroll")                                                           \
      for (int j_ = 0; j_ < 4; ++j_)                                              \
        acc[i_][j_] = __builtin_amdgcn_mfma_f32_16x16x32_bf16(                    \
            aR[i_], bR[j_], acc[i_][j_], 0, 0, 0);                                \
    __builtin_amdgcn_s_setprio(0);                                                \
    __builtin_amdgcn_sched_barrier(0);                                            \
  } while (0)

#define BARX() __builtin_amdgcn_s_barrier()
#define LGKM0X() do { asm volatile("s_waitcnt lgkmcnt(0)");                       \
                      __builtin_amdgcn_sched_barrier(0); } while (0)
#define VMCNT6X() do { asm volatile("s_waitcnt vmcnt(6)");                        \
                       __builtin_amdgcn_sched_barrier(0); } while (0)

  uint32_t curA = 0u, nxtA = 16384u, stgA = 32768u;
  uint32_t curB = 0u, nxtB = 32768u, stgB = 65536u;

  // prologue: stage t0 + t1 (12 loads); drain t0 (leave t1's 6); publish.
  STA128(aGA,       sAb + 0u);
  STA128(aGA + 64,  sAb + 8192u);
  STB128(bGA,       sBb + 0u);
  STB128(bGA + 64,  sBb + 16384u);
  STA128(aGA + 128, sAb + 16384u);
  STA128(aGA + 192, sAb + 16384u + 8192u);
  STB128(bGA + 128, sBb + 32768u);
  STB128(bGA + 192, sBb + 32768u + 16384u);
  aGA += 256; bGA += 256;
  VMCNT6X();
  BARX();

  for (int t = 0; t < NT; ++t) {
    // q0: kh0
    IS_A(curA, 0); IS_B(curB, 0);
    STA128(aGA, sAb + stgA);
    STB128(bGA, sBb + stgB);
    BARX(); LGKM0X(); MFMA16Q(); BARX();
    // q1: kh1 ; drain tile t+1
    IS_A(curA, 1); IS_B(curB, 1);
    STA128(aGA + 64, sAb + stgA + 8192u);
    STB128(bGA + 64, sBb + stgB + 16384u);
    aGA += 128; bGA += 128;
    VMCNT6X();
    BARX(); LGKM0X(); MFMA16Q(); BARX();
    uint32_t ta = curA; curA = nxtA; nxtA = stgA; stgA = ta;
    uint32_t tb = curB; curB = nxtB; nxtB = stgB; stgB = tb;
  }

  asm volatile("s_waitcnt vmcnt(0) lgkmcnt(0)");
  __builtin_amdgcn_sched_barrier(0);

  #pragma unroll
  for (int i = 0; i < 4; ++i)
    #pragma unroll
    for (int j = 0; j < 4; ++j)
      #pragma unroll
      for (int r = 0; r < 4; ++r) {
        size_t row = bm + wm + i * 16 + quad * 4 + r;
        size_t col = bn + wn + j * 16 + l16;
        C[row * (size_t)N + col] = (OutT)acc[i][j][r];
      }

#undef STA128
#undef STB128
#undef DSRD4
#undef IS_A
#undef IS_B
#undef MFMA16Q
#undef BARX
#undef LGKM0X
#undef VMCNT6X
}

// ---------- flash attention v3 (causal, GQA) — 2 q-sets per wave (unchanged) ----------
__global__ __launch_bounds__(256, 2) void attn_kernel(const __bf16* __restrict__ Qr,
                                                      const __bf16* __restrict__ Kr,
                                                      const __bf16* __restrict__ Vt,
                                                      __bf16* __restrict__ O) {
  __shared__ __align__(16) char smem[73728];
  __bf16* Ps = (__bf16*)(smem + 65536);

  const int bid = blockIdx.x;
  const int h = bid & (NH - 1);
  const int j = bid >> 5;
  const int qb = (j < 8) ? (15 - j) : (j - 8);
  const int kvh = h >> 2;
  const int tid = threadIdx.x;
  const int lane = tid & 63, wave = tid >> 6;
  const int quad = lane >> 4, l16 = lane & 15;
  const int sw = l16 & 7;
  const int q0 = qb * 128;

#define STAGE_KV(kbase, bufv) do {                                                 \
    char* kd_ = smem + (bufv) * 16384;                                             \
    char* vd_ = smem + 32768 + (bufv) * 16384;                                     \
    _Pragma("unroll")                                                              \
    for (int pass_ = 0; pass_ < 4; ++pass_) {                                      \
      int c_ = pass_ * 256 + tid;                                                  \
      int row_ = c_ >> 4, ch_ = c_ & 15;                                           \
      int chs_ = ch_ ^ (row_ & 7);                                                 \
      GLD_LDS(&Kr[(size_t)((kbase) + row_) * (NKV * HD) + (size_t)kvh * HD + chs_ * 8], \
              kd_ + c_ * 16);                                                      \
    }                                                                              \
    _Pragma("unroll")                                                              \
    for (int pass_ = 0; pass_ < 4; ++pass_) {                                      \
      int c_ = pass_ * 256 + tid;                                                  \
      int d_ = c_ >> 3, ch_ = c_ & 7;                                              \
      int chs_ = ch_ ^ (d_ & 7);                                                   \
      GLD_LDS(&Vt[((size_t)kvh * HD + d_) * S_LEN + (kbase) + chs_ * 8],           \
              vd_ + c_ * 16);                                                      \
    }                                                                              \
  } while (0)

#define SOFTMAX_SET(scX, m2X, liX, oaccX, maskCond, pfX) do {                      \
    float s_[16];                                                                  \
    _Pragma("unroll")                                                              \
    for (int jt_ = 0; jt_ < 4; ++jt_)                                              \
      _Pragma("unroll")                                                            \
      for (int r_ = 0; r_ < 4; ++r_) s_[jt_ * 4 + r_] = scX[jt_][r_];              \
    if (maskCond) {                                                                \
      int qloc_ = wave * 16 + l16;                                                 \
      _Pragma("unroll")                                                            \
      for (int jt_ = 0; jt_ < 4; ++jt_)                                            \
        _Pragma("unroll")                                                          \
        for (int r_ = 0; r_ < 4; ++r_)                                             \
          if (jt_ * 16 + quad * 4 + r_ > qloc_) s_[jt_ * 4 + r_] = -INFINITY;      \
    }                                                                              \
    float mx_ = s_[0];                                                             \
    _Pragma("unroll")                                                              \
    for (int i_ = 1; i_ < 16; ++i_) mx_ = fmaxf(mx_, s_[i_]);                      \
    mx_ = fmaxf(mx_, __shfl_xor(mx_, 16, 64));                                     \
    mx_ = fmaxf(mx_, __shfl_xor(mx_, 32, 64));                                     \
    float mxs_ = mx_ * C2;                                                         \
    if (!__all(mxs_ <= m2X + 11.54f)) {                                            \
      float m2n_ = fmaxf(m2X, mxs_);                                               \
      float al_ = exp2f(m2X - m2n_);                                               \
      liX *= al_;                                                                  \
      _Pragma("unroll")                                                            \
      for (int dt_ = 0; dt_ < 8; ++dt_) oaccX[dt_] *= al_;                         \
      m2X = m2n_;                                                                  \
    }                                                                              \
    float sum_ = 0.0f;                                                             \
    __bf16* pw_ = Ps + wave * 1024 + l16 * 64;                                     \
    _Pragma("unroll")                                                              \
    for (int jt_ = 0; jt_ < 4; ++jt_) {                                            \
      float e0_ = exp2f(fmaf(s_[jt_*4+0], C2, -m2X));                              \
      float e1_ = exp2f(fmaf(s_[jt_*4+1], C2, -m2X));                              \
      float e2_ = exp2f(fmaf(s_[jt_*4+2], C2, -m2X));                              \
      float e3_ = exp2f(fmaf(s_[jt_*4+3], C2, -m2X));                              \
      sum_ += (e0_ + e1_) + (e2_ + e3_);                                           \
      bf16x4 pk_ = { (__bf16)e0_, (__bf16)e1_, (__bf16)e2_, (__bf16)e3_ };         \
      int ch_ = jt_ * 2 + (quad >> 1);                                             \
      *(bf16x4*)&pw_[((ch_ ^ sw) * 8) + (quad & 1) * 4] = pk_;                     \
    }                                                                              \
    sum_ += __shfl_xor(sum_, 16, 64);                                              \
    sum_ += __shfl_xor(sum_, 32, 64);                                              \
    liX += sum_;                                                                   \
    pfX[0] = *(const bf16x8*)&pw_[((quad) ^ sw) * 8];                              \
    pfX[1] = *(const bf16x8*)&pw_[((4 + quad) ^ sw) * 8];                          \
  } while (0)

  bf16x8 qf[2][4];
  #pragma unroll
  for (int s2 = 0; s2 < 2; ++s2) {
    const __bf16* qp = Qr + (size_t)(q0 + s2 * 64 + wave * 16 + l16) * (NH * HD)
                          + (size_t)h * HD + quad * 8;
    #pragma unroll
    for (int kk = 0; kk < 4; ++kk) qf[s2][kk] = *(const bf16x8*)(qp + kk * 32);
  }
  f32x4 oacc[2][8] = {};
  float m2[2] = { -INFINITY, -INFINITY }, l_i[2] = { 0.0f, 0.0f };
  const float C2 = SCALE_F * 1.4426950408889634f;
  bf16x8 pf0[2], pf1[2];

  int buf = 0;
  STAGE_KV(0, 0);
  for (int kb = 0; kb <= q0; kb += 64) {
    __syncthreads();
    STAGE_KV(kb + 64, buf ^ 1);

    const __bf16* Ks = (const __bf16*)(smem + buf * 16384);
    const __bf16* Vs = (const __bf16*)(smem + 32768 + buf * 16384);

    f32x4 sc0[4] = {}, sc1[4] = {};
    __builtin_amdgcn_s_setprio(1);
    for (int jt = 0; jt < 4; ++jt)
      for (int kk = 0; kk < 4; ++kk) {
        bf16x8 kf = *(const bf16x8*)&Ks[(jt * 16 + l16) * 128 + ((kk * 4 + quad) ^ sw) * 8];
        sc0[jt] = __builtin_amdgcn_mfma_f32_16x16x32_bf16(kf, qf[0][kk], sc0[jt], 0, 0, 0);
        sc1[jt] = __builtin_amdgcn_mfma_f32_16x16x32_bf16(kf, qf[1][kk], sc1[jt], 0, 0, 0);
      }
    __builtin_amdgcn_s_setprio(0);

    SOFTMAX_SET(sc0, m2[0], l_i[0], oacc[0], (kb == q0), pf0);
    SOFTMAX_SET(sc1, m2[1], l_i[1], oacc[1], false, pf1);

    __builtin_amdgcn_s_setprio(1);
    for (int half = 0; half < 2; ++half)
      for (int dt = 0; dt < 8; ++dt) {
        bf16x8 vf = *(const bf16x8*)&Vs[(dt * 16 + l16) * 64 + ((half * 4 + quad) ^ sw) * 8];
        oacc[0][dt] = __builtin_amdgcn_mfma_f32_16x16x32_bf16(vf, pf0[half], oacc[0][dt], 0, 0, 0);
        oacc[1][dt] = __builtin_amdgcn_mfma_f32_16x16x32_bf16(vf, pf1[half], oacc[1][dt], 0, 0, 0);
      }
    __builtin_amdgcn_s_setprio(0);
    buf ^= 1;
  }
  {
    __syncthreads();
    const __bf16* Ks = (const __bf16*)(smem + buf * 16384);
    const __bf16* Vs = (const __bf16*)(smem + 32768 + buf * 16384);

    f32x4 sc1[4] = {};
    __builtin_amdgcn_s_setprio(1);
    for (int jt = 0; jt < 4; ++jt)
      for (int kk = 0; kk < 4; ++kk) {
        bf16x8 kf = *(const bf16x8*)&Ks[(jt * 16 + l16) * 128 + ((kk * 4 + quad) ^ sw) * 8];
        sc1[jt] = __builtin_amdgcn_mfma_f32_16x16x32_bf16(kf, qf[1][kk], sc1[jt], 0, 0, 0);
      }
    __builtin_amdgcn_s_setprio(0);

    SOFTMAX_SET(sc1, m2[1], l_i[1], oacc[1], true, pf1);

    __builtin_amdgcn_s_setprio(1);
    for (int half = 0; half < 2; ++half)
      for (int dt = 0; dt < 8; ++dt) {
        bf16x8 vf = *(const bf16x8*)&Vs[(dt * 16 + l16) * 64 + ((half * 4 + quad) ^ sw) * 8];
        oacc[1][dt] = __builtin_amdgcn_mfma_f32_16x16x32_bf16(vf, pf1[half], oacc[1][dt], 0, 0, 0);
      }
    __builtin_amdgcn_s_setprio(0);
  }
  __syncthreads();

#undef STAGE_KV
#undef SOFTMAX_SET

  float* scr = (float*)smem + wave * 2112;
  #pragma unroll
  for (int s2 = 0; s2 < 2; ++s2) {
    float inv = 1.0f / l_i[s2];
    #pragma unroll
    for (int dt = 0; dt < 8; ++dt) {
      f32x4 v = oacc[s2][dt] * inv;
      *(f32x4*)&scr[l16 * 132 + dt * 16 + quad * 4] = v;
    }
    #pragma unroll
    for (int it = 0; it < 4; ++it) {
      int c = it * 64 + lane;
      int row = c >> 4, ch = c & 15;
      const float* sp = &scr[row * 132 + ch * 8];
      f32x4 a = *(const f32x4*)sp;
      f32x4 b = *(const f32x4*)(sp + 4);
      bf16x8 o = { (__bf16)a[0], (__bf16)a[1], (__bf16)a[2], (__bf16)a[3],
                   (__bf16)b[0], (__bf16)b[1], (__bf16)b[2], (__bf16)b[3] };
      *(bf16x8*)&O[(size_t)(q0 + s2 * 64 + wave * 16 + row) * (NH * HD)
                   + (size_t)h * HD + ch * 8] = o;
    }
  }
}

extern "C" void kernel_launch(void* const* d_in, const int* in_sizes, int n_in,
                              void* d_out, int out_size, void* d_ws, size_t ws_size,
                              hipStream_t stream) {
  const float* hidden    = (const float*)d_in[0];
  const int*   positions = (const int*)d_in[1];
  const float* Wqkv      = (const float*)d_in[2];
  const float* Wo        = (const float*)d_in[3];
  float* out = (float*)d_out;

  char* p = (char*)d_ws;
  auto alloc = [&](size_t bytes) { char* r = p; p += (bytes + 255) & ~(size_t)255; return r; };
  __bf16* hid_bf = (__bf16*)alloc((size_t)S_LEN * HID * 2);       // 16 MB (reused as attn_out)
  __bf16* wqkvT  = (__bf16*)alloc((size_t)QKV_N * HID * 2);       // 48 MB  [6144][4096]
  __bf16* woT    = (__bf16*)alloc((size_t)HID * HID * 2);         // 32 MB  [4096][4096]
  __bf16* qkv    = (__bf16*)alloc((size_t)S_LEN * QKV_N * 2);     // 24 MB
  __bf16* Qr     = (__bf16*)alloc((size_t)S_LEN * NH * HD * 2);   // 16 MB
  __bf16* Kr     = (__bf16*)alloc((size_t)S_LEN * NKV * HD * 2);  // 4 MB
  __bf16* Vt     = (__bf16*)alloc((size_t)S_LEN * NKV * HD * 2);  // 4 MB
  __bf16* attn   = hid_bf;  // hidden_bf16 dead after GEMM1

  // 1: cast + both weight transposes
  fused_prep_kernel<<<12288, 256, 0, stream>>>(hidden, hid_bf, Wqkv, wqkvT, Wo, woT);
  // 2: QKV GEMM (256^2 tiles, 192 blocks = 1 round)
  gemm8p_kernel<__bf16><<<dim3(QKV_N / 256, S_LEN / 256, 1), 512, 0, stream>>>(
      hid_bf, wqkvT, qkv, qkv, S_LEN, QKV_N, HID, HID);
  // 3: rope + V transpose
  fused_rope_tpv_kernel<<<22528, 256, 0, stream>>>(qkv, positions, Qr, Kr, Vt);
  // 4: attention (QBLK=128, 512 blocks)
  attn_kernel<<<NH * (S_LEN / 128), 256, 0, stream>>>(Qr, Kr, Vt, attn);
  // 5: O-projection (128x256 tiles, 256 blocks = full CU coverage, 1 round)
  gemm128_kernel<float><<<dim3(HID / 256, S_LEN / 128, 1), 512, 0, stream>>>(
      attn, woT, out, S_LEN, HID, HID);
}

// Round 10
// 451.264 us; speedup vs baseline: 1.0704x; 1.0704x over previous
//
#include <hip/hip_runtime.h>
#include <math.h>
#include <stdint.h>

// Problem constants
#define S_LEN 2048
#define HID 4096
#define NH 32
#define NKV 8
#define HD 128
#define QKV_N ((NH + 2*NKV) * HD)   // 6144
#define NQK (NH + NKV)              // 40
static __device__ __constant__ const float SCALE_F = 0.08838834764831845f; // 128^-0.5

typedef __bf16 bf16x8 __attribute__((ext_vector_type(8)));
typedef __bf16 bf16x4 __attribute__((ext_vector_type(4)));
typedef float  f32x4  __attribute__((ext_vector_type(4)));
typedef uint32_t u32x4 __attribute__((ext_vector_type(4)));

#define GLD_LDS(gptr, lptr) \
  __builtin_amdgcn_global_load_lds( \
      (const __attribute__((address_space(1))) uint32_t*)(gptr), \
      (__attribute__((address_space(3))) uint32_t*)(lptr), 16, 0, 0)

// ---------- 64x64 transpose+cast tile helper: out[c][r] = (bf16)in[r][c] ----------
__device__ __forceinline__ void tp64(const float* __restrict__ in, __bf16* __restrict__ out,
                                     int R, int C, int bx, int by, int tid, float* tile) {
  int lr = tid >> 4;           // 0..15
  int lc = (tid & 15) * 4;     // 0..60
  #pragma unroll
  for (int p = 0; p < 4; ++p) {
    int r = p * 16 + lr;
    const float4 v = *(const float4*)&in[(size_t)(by + r) * C + bx + lc];
    float* t = &tile[r * 65 + lc];
    t[0] = v.x; t[1] = v.y; t[2] = v.z; t[3] = v.w;
  }
  __syncthreads();
  int oc = tid >> 5;           // 0..7
  int orr = (tid & 31) * 2;
  #pragma unroll
  for (int p = 0; p < 8; ++p) {
    int c = p * 8 + oc;
    float v0 = tile[orr * 65 + c];
    float v1 = tile[(orr + 1) * 65 + c];
    __bf16 b2[2] = { (__bf16)v0, (__bf16)v1 };
    *(uint32_t*)&out[(size_t)(bx + c) * R + by + orr] = *(uint32_t*)b2;
  }
}

// ---------- fused prep: cast hidden -> bf16 | transpose Wqkv ----------
// (R10: Wo transpose moved into the attention launch — it has no consumer until
// the final GEMM, so it backfills attn's causal-imbalance tail instead of
// serializing before the QKV GEMM.)
__global__ __launch_bounds__(256) void fused_prep_kernel(const float* __restrict__ hidden,
                                                         __bf16* __restrict__ hid_bf,
                                                         const float* __restrict__ Wqkv,
                                                         __bf16* __restrict__ wqkvT) {
  __shared__ float tile[64 * 65];
  const int b = blockIdx.x;
  const int tid = threadIdx.x;
  if (b < 2048) {
    const float4* in4 = (const float4*)hidden;
    int i = b * 256 + tid;
    #pragma unroll
    for (int k = 0; k < 4; ++k) {
      float4 v = in4[i + k * 524288];
      bf16x4 o = { (__bf16)v.x, (__bf16)v.y, (__bf16)v.z, (__bf16)v.w };
      *(bf16x4*)(hid_bf + (size_t)(i + k * 524288) * 4) = o;
    }
  } else {
    int id = b - 2048;                 // 96 x 64 tiles
    int bx = (id % 96) * 64, by = (id / 96) * 64;
    tp64(Wqkv, wqkvT, HID, QKV_N, bx, by, tid, tile);
  }
}

// ---------- fused rope + V-transpose ----------
__global__ __launch_bounds__(256) void fused_rope_tpv_kernel(const __bf16* __restrict__ qkv,
                                                             const int* __restrict__ pos,
                                                             __bf16* __restrict__ Qr,
                                                             __bf16* __restrict__ Kr,
                                                             __bf16* __restrict__ Vt) {
  __shared__ __bf16 tile[32][33];
  const int b = blockIdx.x;
  const int tid = threadIdx.x;
  if (b < 20480) {
    int idx = b * 256 + tid;
    int half = idx & 63;
    int t = idx >> 6;
    int hh = t % NQK;
    int s = t / NQK;
    if (s >= S_LEN) return;
    float p = (float)pos[s];
    float inv_freq = exp2f((float)half * -0.2076205059304601f);
    float ang = p * inv_freq;
    float cs = cosf(ang), sn = sinf(ang);
    const __bf16* src; __bf16* dst;
    if (hh < NH) {
      src = qkv + (size_t)s * QKV_N + (size_t)hh * HD;
      dst = Qr + ((size_t)s * NH + hh) * HD;
    } else {
      int kh = hh - NH;
      src = qkv + (size_t)s * QKV_N + (size_t)NH * HD + (size_t)kh * HD;
      dst = Kr + ((size_t)s * NKV + kh) * HD;
    }
    float x1 = (float)src[half], x2 = (float)src[half + 64];
    dst[half]      = (__bf16)(x1 * cs - x2 * sn);
    dst[half + 64] = (__bf16)(x2 * cs + x1 * sn);
  } else {
    int id = b - 20480;
    int sb = (id & 63) * 32;
    int db = ((id >> 6) & 3) * 32;
    int kvh = id >> 8;
    int tx = tid & 31, ty = tid >> 5;
    const __bf16* src = qkv + (size_t)(NH + NKV) * HD + (size_t)kvh * HD;
    for (int i = 0; i < 32; i += 8)
      tile[ty + i][tx] = src[(size_t)(sb + ty + i) * QKV_N + db + tx];
    __syncthreads();
    for (int i = 0; i < 32; i += 8)
      Vt[((size_t)kvh * HD + db + ty + i) * S_LEN + sb + tx] = tile[tx][ty + i];
  }
}

// ===================================================================================
// 256x256-tile 8-phase bf16 GEMM — REVERTED to the R4 pipelined schedule (R9's
// m201-style in-phase reads measured WORSE: 110.8 vs 101 µs, MfmaUtil 39 vs 45).
// Phase p = [even: vmcnt(4)] ; ISSUE ds_reads for p+1 ; s_barrier ; lgkmcnt(4|8) ;
// 16xMFMA(p) ; STAGE. Hazard ledger as verified in R4.
// ===================================================================================
template <typename OutT>
__global__ __launch_bounds__(512, 2) void gemm8p_kernel(const __bf16* __restrict__ A,
                                                        const __bf16* __restrict__ Bt,
                                                        OutT* __restrict__ C0,
                                                        OutT* __restrict__ C1,
                                                        int M, int N, int Kext, int ld) {
  __shared__ __align__(16) __bf16 sA[2][2][256 * 32];
  __shared__ __align__(16) __bf16 sB[2][2][256 * 32];
  const int tid = threadIdx.x;
  const int lane = tid & 63;
  const int wave = tid >> 6;
  const int quad = lane >> 4;
  const int l16 = lane & 15;
  const int wm = (wave >> 2) * 128;
  const int wn = (wave & 3) * 64;

  const int z = blockIdx.z;
  A += (size_t)z * Kext;
  Bt += (size_t)z * Kext;
  OutT* __restrict__ C = z ? C1 : C0;

  const int nx = gridDim.x;
  size_t bm, bn;
  if (gridDim.y == 8 && (nx & 7) == 0) {
    int lin = blockIdx.y * nx + blockIdx.x;
    int j = lin >> 3, xcd = lin & 7;
    bm = (size_t)(j & 7) * 256;
    bn = (size_t)(xcd * (nx >> 3) + (j >> 3)) * 256;
  } else {
    bm = (size_t)blockIdx.y * 256;
    bn = (size_t)blockIdx.x * 256;
  }

  const int NT = Kext >> 6;
  const int rsw = (l16 >> 1) & 3;

  f32x4 acc[8][4] = {};
  bf16x8 aR[2][4], bR[2][4];

  const int row0 = tid >> 2;
  const int chL = (tid & 3) ^ ((tid >> 3) & 3);
  const uint64_t off128 = (uint64_t)128 * ld * 2;
  uint64_t aGA = (uint64_t)(uintptr_t)A + ((bm + row0) * (size_t)ld) * 2 + (size_t)chL * 16;
  uint64_t bGA = (uint64_t)(uintptr_t)Bt + ((bn + row0) * (size_t)ld) * 2 + (size_t)chL * 16;

  typedef __attribute__((address_space(3))) __bf16 lds_bf16;
  const uint32_t sAb = (uint32_t)(uintptr_t)(lds_bf16*)&sA[0][0][0];
  const uint32_t sBb = (uint32_t)(uintptr_t)(lds_bf16*)&sB[0][0][0];
  const uint32_t wlds = (uint32_t)__builtin_amdgcn_readfirstlane(wave * 1024);
  const uint32_t aBase = sAb + (uint32_t)(((wm + l16) * 32 + (quad ^ rsw) * 8) * 2);
  const uint32_t bBase = sBb + (uint32_t)(((wn + l16) * 32 + (quad ^ rsw) * 8) * 2);

#define LDSA(bf, kk) (sAb + (bf) * 32768u + (kk) * 16384u)
#define LDSB(bf, kk) (sBb + (bf) * 32768u + (kk) * 16384u)

#define STAGE_ASM(ga, ldsbase) \
  asm volatile("s_mov_b32 m0, %0\n\t" \
               "global_load_lds_dwordx4 %2, off\n\t" \
               "s_mov_b32 m0, %1\n\t" \
               "global_load_lds_dwordx4 %3, off" \
               :: "s"((ldsbase) + wlds), "s"((ldsbase) + wlds + 8192u), \
                  "v"(ga), "v"((ga) + off128) : "memory")

#define DSRD4(dst, baseaddr) do {                                                 \
    u32x4 t0_, t1_, t2_, t3_;                                                     \
    asm volatile("ds_read_b128 %0, %4\n\t"                                        \
                 "ds_read_b128 %1, %4 offset:1024\n\t"                            \
                 "ds_read_b128 %2, %4 offset:2048\n\t"                            \
                 "ds_read_b128 %3, %4 offset:3072"                                \
                 : "=&v"(t0_), "=&v"(t1_), "=&v"(t2_), "=&v"(t3_)                 \
                 : "v"(baseaddr));                                                \
    dst[0] = __builtin_bit_cast(bf16x8, t0_);                                     \
    dst[1] = __builtin_bit_cast(bf16x8, t1_);                                     \
    dst[2] = __builtin_bit_cast(bf16x8, t2_);                                     \
    dst[3] = __builtin_bit_cast(bf16x8, t3_);                                     \
  } while (0)

#define ISSUE_A(set, bf, kk, ih) DSRD4(aR[set], aBase + (bf) * 32768u + (kk) * 16384u + (ih) * 4096u)
#define ISSUE_B(set, bf, kk)     DSRD4(bR[set], bBase + (bf) * 32768u + (kk) * 16384u)

#define MFMA16(as, bs, ih) do {                                                   \
    __builtin_amdgcn_s_setprio(1);                                                \
    _Pragma("unroll")                                                             \
    for (int i_ = 0; i_ < 4; ++i_)                                                \
      _Pragma("unroll")                                                           \
      for (int j_ = 0; j_ < 4; ++j_)                                              \
        acc[(ih) * 4 + i_][j_] = __builtin_amdgcn_mfma_f32_16x16x32_bf16(         \
            aR[as][i_], bR[bs][j_], acc[(ih) * 4 + i_][j_], 0, 0, 0);             \
    __builtin_amdgcn_s_setprio(0);                                                \
    __builtin_amdgcn_sched_barrier(0);                                            \
  } while (0)

#define BAR() __builtin_amdgcn_s_barrier()
#define LGKM4() do { asm volatile("s_waitcnt lgkmcnt(4)");                        \
                     __builtin_amdgcn_sched_barrier(0); } while (0)
#define LGKM8() do { asm volatile("s_waitcnt lgkmcnt(8)");                        \
                     __builtin_amdgcn_sched_barrier(0); } while (0)
#define VMCNT4() do { asm volatile("s_waitcnt vmcnt(4)");                         \
                      __builtin_amdgcn_sched_barrier(0); } while (0)

  STAGE_ASM(aGA,        LDSA(0, 0));
  STAGE_ASM(bGA,        LDSB(0, 0));
  STAGE_ASM(aGA + 64,   LDSA(0, 1));
  STAGE_ASM(bGA + 64,   LDSB(0, 1));
  STAGE_ASM(aGA + 128,  LDSA(1, 0));
  STAGE_ASM(bGA + 128,  LDSB(1, 0));
  aGA += 192; bGA += 192;
  asm volatile("s_waitcnt vmcnt(8)");
  __builtin_amdgcn_sched_barrier(0);
  BAR();
  ISSUE_A(0, 0, 0, 0); ISSUE_B(0, 0, 0);

  for (int u = 0; u < (NT >> 1); ++u) {
    VMCNT4();
    ISSUE_A(1, 0, 0, 1);
    BAR();
    LGKM4();
    MFMA16(0, 0, 0);
    STAGE_ASM(aGA, LDSA(1, 1)); aGA += 64;
    ISSUE_A(0, 0, 1, 0); ISSUE_B(1, 0, 1);
    BAR();
    LGKM8();
    MFMA16(1, 0, 1);
    STAGE_ASM(bGA, LDSB(1, 1)); bGA += 64;
    VMCNT4();
    ISSUE_A(1, 0, 1, 1);
    BAR();
    LGKM4();
    MFMA16(0, 1, 0);
    STAGE_ASM(aGA, LDSA(0, 0)); aGA += 64;
    ISSUE_A(0, 1, 0, 0); ISSUE_B(0, 1, 0);
    BAR();
    LGKM8();
    MFMA16(1, 1, 1);
    STAGE_ASM(bGA, LDSB(0, 0)); bGA += 64;
    VMCNT4();
    ISSUE_A(1, 1, 0, 1);
    BAR();
    LGKM4();
    MFMA16(0, 0, 0);
    STAGE_ASM(aGA, LDSA(0, 1)); aGA += 64;
    ISSUE_A(0, 1, 1, 0); ISSUE_B(1, 1, 1);
    BAR();
    LGKM8();
    MFMA16(1, 0, 1);
    STAGE_ASM(bGA, LDSB(0, 1)); bGA += 64;
    VMCNT4();
    ISSUE_A(1, 1, 1, 1);
    BAR();
    LGKM4();
    MFMA16(0, 1, 0);
    STAGE_ASM(aGA, LDSA(1, 0)); aGA += 64;
    ISSUE_A(0, 0, 0, 0); ISSUE_B(0, 0, 0);
    BAR();
    LGKM8();
    MFMA16(1, 1, 1);
    STAGE_ASM(bGA, LDSB(1, 0)); bGA += 64;
  }

  asm volatile("s_waitcnt vmcnt(0) lgkmcnt(0)");
  __builtin_amdgcn_sched_barrier(0);

  #pragma unroll
  for (int i = 0; i < 8; ++i)
    #pragma unroll
    for (int j = 0; j < 4; ++j)
      #pragma unroll
      for (int r = 0; r < 4; ++r) {
        size_t row = bm + wm + i * 16 + quad * 4 + r;
        size_t col = bn + wn + j * 16 + l16;
        C[row * (size_t)N + col] = (OutT)acc[i][j][r];
      }

#undef LDSA
#undef LDSB
#undef STAGE_ASM
#undef DSRD4
#undef ISSUE_A
#undef ISSUE_B
#undef MFMA16
#undef BAR
#undef LGKM4
#undef LGKM8
#undef VMCNT4
}

// ===================================================================================
// BM=128 x BN=256 O-proj GEMM with m201-style phase timing (R9 — kept; estimated
// neutral-to-slightly-better by subtraction vs R8's pipelined variant).
// ===================================================================================
template <typename OutT>
__global__ __launch_bounds__(512, 2) void gemm128_kernel(const __bf16* __restrict__ A,
                                                         const __bf16* __restrict__ Bt,
                                                         OutT* __restrict__ C,
                                                         int M, int N, int K) {
  __shared__ __align__(16) __bf16 sA[3][2][128 * 32];   // 48 KB
  __shared__ __align__(16) __bf16 sB[3][2][256 * 32];   // 96 KB
  const int tid = threadIdx.x;
  const int lane = tid & 63;
  const int wave = tid >> 6;
  const int quad = lane >> 4;
  const int l16 = lane & 15;
  const int wm = (wave >> 2) * 64;
  const int wn = (wave & 3) * 64;

  const int nx = gridDim.x, ny = gridDim.y;
  const int nwg = nx * ny;
  int lin = blockIdx.y * nx + blockIdx.x;
  size_t bm, bn;
  if ((nwg & 7) == 0) {
    int swz = (lin & 7) * (nwg >> 3) + (lin >> 3);
    bm = (size_t)(swz % ny) * 128;
    bn = (size_t)(swz / ny) * 256;
  } else {
    bm = (size_t)blockIdx.y * 128;
    bn = (size_t)blockIdx.x * 256;
  }

  const int NT = K >> 6;
  const int rsw = (l16 >> 1) & 3;

  f32x4 acc[4][4] = {};
  bf16x8 aR[4], bR[4];

  const int rowA = tid >> 2;
  const int chLs = (tid & 3) ^ ((tid >> 3) & 3);
  const uint64_t off128B = (uint64_t)128 * K * 2;
  uint64_t aGA = (uint64_t)(uintptr_t)A + ((bm + rowA) * (size_t)K) * 2 + (size_t)chLs * 16;
  uint64_t bGA = (uint64_t)(uintptr_t)Bt + ((bn + rowA) * (size_t)K) * 2 + (size_t)chLs * 16;

  typedef __attribute__((address_space(3))) __bf16 lds_bf16;
  const uint32_t sAb = (uint32_t)(uintptr_t)(lds_bf16*)&sA[0][0][0];
  const uint32_t sBb = (uint32_t)(uintptr_t)(lds_bf16*)&sB[0][0][0];
  const uint32_t wlds = (uint32_t)__builtin_amdgcn_readfirstlane(wave * 1024);
  const uint32_t aBase = sAb + (uint32_t)(((wm + l16) * 32 + (quad ^ rsw) * 8) * 2);
  const uint32_t bBase = sBb + (uint32_t)(((wn + l16) * 32 + (quad ^ rsw) * 8) * 2);

#define STA128(ga, ldsoff) \
  asm volatile("s_mov_b32 m0, %0\n\t" \
               "global_load_lds_dwordx4 %1, off" \
               :: "s"((ldsoff) + wlds), "v"(ga) : "memory")

#define STB128(ga, ldsoff) \
  asm volatile("s_mov_b32 m0, %0\n\t" \
               "global_load_lds_dwordx4 %2, off\n\t" \
               "s_mov_b32 m0, %1\n\t" \
               "global_load_lds_dwordx4 %3, off" \
               :: "s"((ldsoff) + wlds), "s"((ldsoff) + wlds + 8192u), \
                  "v"(ga), "v"((ga) + off128B) : "memory")

#define DSRD4(dst, baseaddr) do {                                                 \
    u32x4 t0_, t1_, t2_, t3_;                                                     \
    asm volatile("ds_read_b128 %0, %4\n\t"                                        \
                 "ds_read_b128 %1, %4 offset:1024\n\t"                            \
                 "ds_read_b128 %2, %4 offset:2048\n\t"                            \
                 "ds_read_b128 %3, %4 offset:3072"                                \
                 : "=&v"(t0_), "=&v"(t1_), "=&v"(t2_), "=&v"(t3_)                 \
                 : "v"(baseaddr));                                                \
    dst[0] = __builtin_bit_cast(bf16x8, t0_);                                     \
    dst[1] = __builtin_bit_cast(bf16x8, t1_);                                     \
    dst[2] = __builtin_bit_cast(bf16x8, t2_);                                     \
    dst[3] = __builtin_bit_cast(bf16x8, t3_);                                     \
  } while (0)

#define IS_A(aoff, kh) DSRD4(aR, aBase + (aoff) + (kh) * 8192u)
#define IS_B(boff, kh) DSRD4(bR, bBase + (boff) + (kh) * 16384u)

#define MFMA16Q() do {                                                            \
    __builtin_amdgcn_s_setprio(1);                                                \
    _Pragma("unroll")                                                             \
    for (int i_ = 0; i_ < 4; ++i_)                                                \
      _Pragma("unroll")                                                           \
      for (int j_ = 0; j_ < 4; ++j_)                                              \
        acc[i_][j_] = __builtin_amdgcn_mfma_f32_16x16x32_bf16(                    \
            aR[i_], bR[j_], acc[i_][j_], 0, 0, 0);                                \
    __builtin_amdgcn_s_setprio(0);                                                \
    __builtin_amdgcn_sched_barrier(0);                                            \
  } while (0)

#define BARX() __builtin_amdgcn_s_barrier()
#define LGKM0X() do { asm volatile("s_waitcnt lgkmcnt(0)");                       \
                      __builtin_amdgcn_sched_barrier(0); } while (0)
#define VMCNT6X() do { asm volatile("s_waitcnt vmcnt(6)");                        \
                       __builtin_amdgcn_sched_barrier(0); } while (0)

  uint32_t curA = 0u, nxtA = 16384u, stgA = 32768u;
  uint32_t curB = 0u, nxtB = 32768u, stgB = 65536u;

  STA128(aGA,       sAb + 0u);
  STA128(aGA + 64,  sAb + 8192u);
  STB128(bGA,       sBb + 0u);
  STB128(bGA + 64,  sBb + 16384u);
  STA128(aGA + 128, sAb + 16384u);
  STA128(aGA + 192, sAb + 16384u + 8192u);
  STB128(bGA + 128, sBb + 32768u);
  STB128(bGA + 192, sBb + 32768u + 16384u);
  aGA += 256; bGA += 256;
  VMCNT6X();
  BARX();

  for (int t = 0; t < NT; ++t) {
    IS_A(curA, 0); IS_B(curB, 0);
    STA128(aGA, sAb + stgA);
    STB128(bGA, sBb + stgB);
    BARX(); LGKM0X(); MFMA16Q(); BARX();
    IS_A(curA, 1); IS_B(curB, 1);
    STA128(aGA + 64, sAb + stgA + 8192u);
    STB128(bGA + 64, sBb + stgB + 16384u);
    aGA += 128; bGA += 128;
    VMCNT6X();
    BARX(); LGKM0X(); MFMA16Q(); BARX();
    uint32_t ta = curA; curA = nxtA; nxtA = stgA; stgA = ta;
    uint32_t tb = curB; curB = nxtB; nxtB = stgB; stgB = tb;
  }

  asm volatile("s_waitcnt vmcnt(0) lgkmcnt(0)");
  __builtin_amdgcn_sched_barrier(0);

  #pragma unroll
  for (int i = 0; i < 4; ++i)
    #pragma unroll
    for (int j = 0; j < 4; ++j)
      #pragma unroll
      for (int r = 0; r < 4; ++r) {
        size_t row = bm + wm + i * 16 + quad * 4 + r;
        size_t col = bn + wn + j * 16 + l16;
        C[row * (size_t)N + col] = (OutT)acc[i][j][r];
      }

#undef STA128
#undef STB128
#undef DSRD4
#undef IS_A
#undef IS_B
#undef MFMA16Q
#undef BARX
#undef LGKM0X
#undef VMCNT6X
}

// ---------- flash attention (causal, GQA, 2 q-sets/wave) + Wo-transpose backfill ----------
// Blocks [0,512): attention (unchanged from R7). Blocks [512,4608): 64x64 Wo
// transpose tiles — independent work that backfills attn's causal load-imbalance
// tail. woT is consumed by gemm128, stream-ordered after this kernel.
__global__ __launch_bounds__(256, 2) void attn_kernel(const __bf16* __restrict__ Qr,
                                                      const __bf16* __restrict__ Kr,
                                                      const __bf16* __restrict__ Vt,
                                                      __bf16* __restrict__ O,
                                                      const float* __restrict__ Wo,
                                                      __bf16* __restrict__ woT) {
  __shared__ __align__(16) char smem[73728];
  __bf16* Ps = (__bf16*)(smem + 65536);

  const int bid = blockIdx.x;
  const int tid = threadIdx.x;
  if (bid >= 512) {            // Wo transpose tile (uses 16.6 KB of smem)
    int id = bid - 512;
    int bx = (id & 63) * 64, by = (id >> 6) * 64;
    tp64(Wo, woT, HID, HID, bx, by, tid, (float*)smem);
    return;
  }

  const int h = bid & (NH - 1);
  const int j = bid >> 5;
  const int qb = (j < 8) ? (15 - j) : (j - 8);
  const int kvh = h >> 2;
  const int lane = tid & 63, wave = tid >> 6;
  const int quad = lane >> 4, l16 = lane & 15;
  const int sw = l16 & 7;
  const int q0 = qb * 128;

#define STAGE_KV(kbase, bufv) do {                                                 \
    char* kd_ = smem + (bufv) * 16384;                                             \
    char* vd_ = smem + 32768 + (bufv) * 16384;                                     \
    _Pragma("unroll")                                                              \
    for (int pass_ = 0; pass_ < 4; ++pass_) {                                      \
      int c_ = pass_ * 256 + tid;                                                  \
      int row_ = c_ >> 4, ch_ = c_ & 15;                                           \
      int chs_ = ch_ ^ (row_ & 7);                                                 \
      GLD_LDS(&Kr[(size_t)((kbase) + row_) * (NKV * HD) + (size_t)kvh * HD + chs_ * 8], \
              kd_ + c_ * 16);                                                      \
    }                                                                              \
    _Pragma("unroll")                                                              \
    for (int pass_ = 0; pass_ < 4; ++pass_) {                                      \
      int c_ = pass_ * 256 + tid;                                                  \
      int d_ = c_ >> 3, ch_ = c_ & 7;                                              \
      int chs_ = ch_ ^ (d_ & 7);                                                   \
      GLD_LDS(&Vt[((size_t)kvh * HD + d_) * S_LEN + (kbase) + chs_ * 8],           \
              vd_ + c_ * 16);                                                      \
    }                                                                              \
  } while (0)

#define SOFTMAX_SET(scX, m2X, liX, oaccX, maskCond, pfX) do {                      \
    float s_[16];                                                                  \
    _Pragma("unroll")                                                              \
    for (int jt_ = 0; jt_ < 4; ++jt_)                                              \
      _Pragma("unroll")                                                            \
      for (int r_ = 0; r_ < 4; ++r_) s_[jt_ * 4 + r_] = scX[jt_][r_];              \
    if (maskCond) {                                                                \
      int qloc_ = wave * 16 + l16;                                                 \
      _Pragma("unroll")                                                            \
      for (int jt_ = 0; jt_ < 4; ++jt_)                                            \
        _Pragma("unroll")                                                          \
        for (int r_ = 0; r_ < 4; ++r_)                                             \
          if (jt_ * 16 + quad * 4 + r_ > qloc_) s_[jt_ * 4 + r_] = -INFINITY;      \
    }                                                                              \
    float mx_ = s_[0];                                                             \
    _Pragma("unroll")                                                              \
    for (int i_ = 1; i_ < 16; ++i_) mx_ = fmaxf(mx_, s_[i_]);                      \
    mx_ = fmaxf(mx_, __shfl_xor(mx_, 16, 64));                                     \
    mx_ = fmaxf(mx_, __shfl_xor(mx_, 32, 64));                                     \
    float mxs_ = mx_ * C2;                                                         \
    if (!__all(mxs_ <= m2X + 11.54f)) {                                            \
      float m2n_ = fmaxf(m2X, mxs_);                                               \
      float al_ = exp2f(m2X - m2n_);                                               \
      liX *= al_;                                                                  \
      _Pragma("unroll")                                                            \
      for (int dt_ = 0; dt_ < 8; ++dt_) oaccX[dt_] *= al_;                         \
      m2X = m2n_;                                                                  \
    }                                                                              \
    float sum_ = 0.0f;                                                             \
    __bf16* pw_ = Ps + wave * 1024 + l16 * 64;                                     \
    _Pragma("unroll")                                                              \
    for (int jt_ = 0; jt_ < 4; ++jt_) {                                            \
      float e0_ = exp2f(fmaf(s_[jt_*4+0], C2, -m2X));                              \
      float e1_ = exp2f(fmaf(s_[jt_*4+1], C2, -m2X));                              \
      float e2_ = exp2f(fmaf(s_[jt_*4+2], C2, -m2X));                              \
      float e3_ = exp2f(fmaf(s_[jt_*4+3], C2, -m2X));                              \
      sum_ += (e0_ + e1_) + (e2_ + e3_);                                           \
      bf16x4 pk_ = { (__bf16)e0_, (__bf16)e1_, (__bf16)e2_, (__bf16)e3_ };         \
      int ch_ = jt_ * 2 + (quad >> 1);                                             \
      *(bf16x4*)&pw_[((ch_ ^ sw) * 8) + (quad & 1) * 4] = pk_;                     \
    }                                                                              \
    sum_ += __shfl_xor(sum_, 16, 64);                                              \
    sum_ += __shfl_xor(sum_, 32, 64);                                              \
    liX += sum_;                                                                   \
    pfX[0] = *(const bf16x8*)&pw_[((quad) ^ sw) * 8];                              \
    pfX[1] = *(const bf16x8*)&pw_[((4 + quad) ^ sw) * 8];                          \
  } while (0)

  bf16x8 qf[2][4];
  #pragma unroll
  for (int s2 = 0; s2 < 2; ++s2) {
    const __bf16* qp = Qr + (size_t)(q0 + s2 * 64 + wave * 16 + l16) * (NH * HD)
                          + (size_t)h * HD + quad * 8;
    #pragma unroll
    for (int kk = 0; kk < 4; ++kk) qf[s2][kk] = *(const bf16x8*)(qp + kk * 32);
  }
  f32x4 oacc[2][8] = {};
  float m2[2] = { -INFINITY, -INFINITY }, l_i[2] = { 0.0f, 0.0f };
  const float C2 = SCALE_F * 1.4426950408889634f;
  bf16x8 pf0[2], pf1[2];

  int buf = 0;
  STAGE_KV(0, 0);
  for (int kb = 0; kb <= q0; kb += 64) {
    __syncthreads();
    STAGE_KV(kb + 64, buf ^ 1);

    const __bf16* Ks = (const __bf16*)(smem + buf * 16384);
    const __bf16* Vs = (const __bf16*)(smem + 32768 + buf * 16384);

    f32x4 sc0[4] = {}, sc1[4] = {};
    __builtin_amdgcn_s_setprio(1);
    for (int jt = 0; jt < 4; ++jt)
      for (int kk = 0; kk < 4; ++kk) {
        bf16x8 kf = *(const bf16x8*)&Ks[(jt * 16 + l16) * 128 + ((kk * 4 + quad) ^ sw) * 8];
        sc0[jt] = __builtin_amdgcn_mfma_f32_16x16x32_bf16(kf, qf[0][kk], sc0[jt], 0, 0, 0);
        sc1[jt] = __builtin_amdgcn_mfma_f32_16x16x32_bf16(kf, qf[1][kk], sc1[jt], 0, 0, 0);
      }
    __builtin_amdgcn_s_setprio(0);

    SOFTMAX_SET(sc0, m2[0], l_i[0], oacc[0], (kb == q0), pf0);
    SOFTMAX_SET(sc1, m2[1], l_i[1], oacc[1], false, pf1);

    __builtin_amdgcn_s_setprio(1);
    for (int half = 0; half < 2; ++half)
      for (int dt = 0; dt < 8; ++dt) {
        bf16x8 vf = *(const bf16x8*)&Vs[(dt * 16 + l16) * 64 + ((half * 4 + quad) ^ sw) * 8];
        oacc[0][dt] = __builtin_amdgcn_mfma_f32_16x16x32_bf16(vf, pf0[half], oacc[0][dt], 0, 0, 0);
        oacc[1][dt] = __builtin_amdgcn_mfma_f32_16x16x32_bf16(vf, pf1[half], oacc[1][dt], 0, 0, 0);
      }
    __builtin_amdgcn_s_setprio(0);
    buf ^= 1;
  }
  {
    __syncthreads();
    const __bf16* Ks = (const __bf16*)(smem + buf * 16384);
    const __bf16* Vs = (const __bf16*)(smem + 32768 + buf * 16384);

    f32x4 sc1[4] = {};
    __builtin_amdgcn_s_setprio(1);
    for (int jt = 0; jt < 4; ++jt)
      for (int kk = 0; kk < 4; ++kk) {
        bf16x8 kf = *(const bf16x8*)&Ks[(jt * 16 + l16) * 128 + ((kk * 4 + quad) ^ sw) * 8];
        sc1[jt] = __builtin_amdgcn_mfma_f32_16x16x32_bf16(kf, qf[1][kk], sc1[jt], 0, 0, 0);
      }
    __builtin_amdgcn_s_setprio(0);

    SOFTMAX_SET(sc1, m2[1], l_i[1], oacc[1], true, pf1);

    __builtin_amdgcn_s_setprio(1);
    for (int half = 0; half < 2; ++half)
      for (int dt = 0; dt < 8; ++dt) {
        bf16x8 vf = *(const bf16x8*)&Vs[(dt * 16 + l16) * 64 + ((half * 4 + quad) ^ sw) * 8];
        oacc[1][dt] = __builtin_amdgcn_mfma_f32_16x16x32_bf16(vf, pf1[half], oacc[1][dt], 0, 0, 0);
      }
    __builtin_amdgcn_s_setprio(0);
  }
  __syncthreads();

#undef STAGE_KV
#undef SOFTMAX_SET

  float* scr = (float*)smem + wave * 2112;
  #pragma unroll
  for (int s2 = 0; s2 < 2; ++s2) {
    float inv = 1.0f / l_i[s2];
    #pragma unroll
    for (int dt = 0; dt < 8; ++dt) {
      f32x4 v = oacc[s2][dt] * inv;
      *(f32x4*)&scr[l16 * 132 + dt * 16 + quad * 4] = v;
    }
    #pragma unroll
    for (int it = 0; it < 4; ++it) {
      int c = it * 64 + lane;
      int row = c >> 4, ch = c & 15;
      const float* sp = &scr[row * 132 + ch * 8];
      f32x4 a = *(const f32x4*)sp;
      f32x4 b = *(const f32x4*)(sp + 4);
      bf16x8 o = { (__bf16)a[0], (__bf16)a[1], (__bf16)a[2], (__bf16)a[3],
                   (__bf16)b[0], (__bf16)b[1], (__bf16)b[2], (__bf16)b[3] };
      *(bf16x8*)&O[(size_t)(q0 + s2 * 64 + wave * 16 + row) * (NH * HD)
                   + (size_t)h * HD + ch * 8] = o;
    }
  }
}

extern "C" void kernel_launch(void* const* d_in, const int* in_sizes, int n_in,
                              void* d_out, int out_size, void* d_ws, size_t ws_size,
                              hipStream_t stream) {
  const float* hidden    = (const float*)d_in[0];
  const int*   positions = (const int*)d_in[1];
  const float* Wqkv      = (const float*)d_in[2];
  const float* Wo        = (const float*)d_in[3];
  float* out = (float*)d_out;

  char* p = (char*)d_ws;
  auto alloc = [&](size_t bytes) { char* r = p; p += (bytes + 255) & ~(size_t)255; return r; };
  __bf16* hid_bf = (__bf16*)alloc((size_t)S_LEN * HID * 2);       // 16 MB (reused as attn_out)
  __bf16* wqkvT  = (__bf16*)alloc((size_t)QKV_N * HID * 2);       // 48 MB  [6144][4096]
  __bf16* woT    = (__bf16*)alloc((size_t)HID * HID * 2);         // 32 MB  [4096][4096]
  __bf16* qkv    = (__bf16*)alloc((size_t)S_LEN * QKV_N * 2);     // 24 MB
  __bf16* Qr     = (__bf16*)alloc((size_t)S_LEN * NH * HD * 2);   // 16 MB
  __bf16* Kr     = (__bf16*)alloc((size_t)S_LEN * NKV * HD * 2);  // 4 MB
  __bf16* Vt     = (__bf16*)alloc((size_t)S_LEN * NKV * HD * 2);  // 4 MB
  __bf16* attn   = hid_bf;  // hidden_bf16 dead after GEMM1

  // 1: cast + Wqkv transpose (Wo transpose deferred into the attn launch)
  fused_prep_kernel<<<8192, 256, 0, stream>>>(hidden, hid_bf, Wqkv, wqkvT);
  // 2: QKV GEMM (256^2 tiles, 192 blocks = 1 round)
  gemm8p_kernel<__bf16><<<dim3(QKV_N / 256, S_LEN / 256, 1), 512, 0, stream>>>(
      hid_bf, wqkvT, qkv, qkv, S_LEN, QKV_N, HID, HID);
  // 3: rope + V transpose
  fused_rope_tpv_kernel<<<22528, 256, 0, stream>>>(qkv, positions, Qr, Kr, Vt);
  // 4: attention (512 blocks) + Wo transpose backfill (4096 blocks)
  attn_kernel<<<512 + 4096, 256, 0, stream>>>(Qr, Kr, Vt, attn, Wo, woT);
  // 5: O-projection (128x256 tiles, 256 blocks = full CU coverage, 1 round)
  gemm128_kernel<float><<<dim3(HID / 256, S_LEN / 128, 1), 512, 0, stream>>>(
      attn, woT, out, S_LEN, HID, HID);
}